// Round 2
// baseline (13.300 us; speedup 1.0000x reference)
//
#include <hip/hip_runtime.h>

// WaveletModel: out[b,k,n] = sum_j x[b, k%8, n + j - 1151] * wav[k%16, j]
//   wav[s,j] = (1 - j^2/sig^2) * exp(-j^2/(2 sig^2)),  sig = scales[s]/(2*pi)
// Structure exploited:
//  - output channel k depends only on d = k%16 (16 distinct convs, replicated 8x)
//  - wavelet is negligible beyond jmax = 12*sigma+4 (residual <= e^-72); scale<=100
//    -> jmax <= ~200 taps (JCAP=512 headroom)
//  - register-tiled R=4 outputs/thread, 4 taps/group: per group 1 ds_read_b128 (x,
//    conflict-free stride-16B) + 1 broadcast b128 (w) + 16 FMA  -> LDS-issue count
//    cut 4x vs scalar version (was the bottleneck at ~12us)

#define NPIX 2304       // N = 48*48
#define NC 8
#define LEFT 1151       // (N-1)//2, 'same' padding left
#define TILE 768        // 3 tiles cover NPIX
#define THREADS 192     // 3 waves; each thread owns 4 contiguous outputs
#define JCAP 512        // max truncated kernel length supported

__global__ __launch_bounds__(THREADS)
void wavelet_conv_kernel(const float* __restrict__ x,
                         const float* __restrict__ scales,
                         float* __restrict__ out) {
    __shared__ float ws[JCAP];
    __shared__ float xp[TILE + JCAP + 4];

    const int bx   = blockIdx.x;      // [0, 384)
    const int pair = bx / 3;          // [0, 128) = b*16 + d
    const int tile = bx - 3 * pair;
    const int b    = pair >> 4;
    const int d    = pair & 15;       // distinct conv index (= k % 16)
    const int c    = d & 7;           // input channel (= k % 8)
    const int t0   = tile * TILE;
    const int tid  = threadIdx.x;

    const float scale  = scales[d];
    const float sigma  = scale * 0.15915494309189535f;   // scale / (2*pi)
    const float inv_s2 = 1.0f / (sigma * sigma);
    int jmax = (int)(12.0f * sigma) + 4;                 // exp(-72) tail cut
    if (jmax > JCAP - 4) jmax = JCAP - 4;
    const int jpad = (jmax + 3) & ~3;                    // multiple of 4
    const int gmax = jpad >> 2;

    // stage truncated wavelet row (values past jmax are <= e^-72, harmless)
    for (int i = tid; i < jpad; i += THREADS) {
        float fj = (float)i;
        float a  = fj * fj * inv_s2;                     // t^2 / sigma^2
        ws[i] = (1.0f - a) * __expf(-0.5f * a);
    }
    // stage zero-padded x window: xp[i] = x[t0 - LEFT + i], i in [0, TILE+jpad+4)
    const float* xrow = x + (size_t)(b * NC + c) * NPIX;
    const int xlen = TILE + jpad + 4;
    for (int i = tid; i < xlen; i += THREADS) {
        int g = t0 - LEFT + i;
        xp[i] = (g >= 0 && g < NPIX) ? xrow[g] : 0.0f;
    }
    __syncthreads();

    // thread t computes outputs n0 = t0 + 4t .. +3 via sliding 8-reg x window
    const int base = 4 * tid;
    const float4* xp4 = reinterpret_cast<const float4*>(xp + base);
    const float4* ws4 = reinterpret_cast<const float4*>(ws);
    float a0 = 0.f, a1 = 0.f, a2 = 0.f, a3 = 0.f;
    float4 xa = xp4[0];
    #pragma unroll 2
    for (int g = 0; g < gmax; ++g) {
        float4 xb = xp4[g + 1];
        float4 wq = ws4[g];
        // tap 4g+0
        a0 = fmaf(xa.x, wq.x, a0);
        a1 = fmaf(xa.y, wq.x, a1);
        a2 = fmaf(xa.z, wq.x, a2);
        a3 = fmaf(xa.w, wq.x, a3);
        // tap 4g+1
        a0 = fmaf(xa.y, wq.y, a0);
        a1 = fmaf(xa.z, wq.y, a1);
        a2 = fmaf(xa.w, wq.y, a2);
        a3 = fmaf(xb.x, wq.y, a3);
        // tap 4g+2
        a0 = fmaf(xa.z, wq.z, a0);
        a1 = fmaf(xa.w, wq.z, a1);
        a2 = fmaf(xb.x, wq.z, a2);
        a3 = fmaf(xb.y, wq.z, a3);
        // tap 4g+3
        a0 = fmaf(xa.w, wq.w, a0);
        a1 = fmaf(xb.x, wq.w, a1);
        a2 = fmaf(xb.y, wq.w, a2);
        a3 = fmaf(xb.z, wq.w, a3);
        xa = xb;
    }

    // replicate to all 8 duplicate channels k = d + 16*kk (coalesced float4)
    const int n0 = t0 + base;
    float4 v = make_float4(a0, a1, a2, a3);
    #pragma unroll
    for (int kk = 0; kk < 8; ++kk) {
        int k = d + 16 * kk;
        *reinterpret_cast<float4*>(out + (size_t)(b * 128 + k) * NPIX + n0) = v;
    }
}

extern "C" void kernel_launch(void* const* d_in, const int* in_sizes, int n_in,
                              void* d_out, int out_size, void* d_ws, size_t ws_size,
                              hipStream_t stream) {
    const float* x      = (const float*)d_in[0];
    const float* scales = (const float*)d_in[1];
    float* out          = (float*)d_out;
    wavelet_conv_kernel<<<384, THREADS, 0, stream>>>(x, scales, out);
}